// Round 7
// baseline (443.432 us; speedup 1.0000x reference)
//
#include <hip/hip_runtime.h>
#include <hip/hip_cooperative_groups.h>

namespace cg = cooperative_groups;

#define NB 16
#define NN 1024
#define NBN (NB * NN)
#define MAXN 128
#define NU 8
#define NH 12
#define NMLP 16
#define KC 16
#define EGB 512    // k_eg block size
#define GRID2 256  // cooperative grid (1 block/CU with margin)
#define BLK 512    // cooperative block size

// H-tile swizzle: float4 quadrant c of row j (16 floats) -> uniform over the
// 8 aligned bank-groups. (b64/16-group variant measured WORSE in R4; b128 it is.)
#define QSW(j, c) (((j) << 4) + ((((c) ^ (((j) >> 2) & 3)) & 3) << 2))
// u-row swizzle (8 floats, 2 granules): staging writes by consecutive tid are
// conflict-free (8 consecutive j cover all 8 groups); random reads uniform.
#define USW(j, c) (((j) << 3) + ((((c) ^ (((j) >> 2) & 1)) & 1) << 2))

// LDS weight-cache word offsets
#define W_M1   0
#define W_M1B  384
#define W_M2   400
#define W_M2B  528
#define W_GIH  536
#define W_GHH  896
#define W_BIH  1328
#define W_BHH  1364
#define W_W2   1400
#define W_W2B  1496   // W2b + b2
#define W_R1   1504
#define W_R1B  1632
#define W_R2   1648
#define W_R2B  1680
#define W_W1   1682
#define W_W1B  1698   // W1b + b1
#define W_SZ   1712

struct KParams {
  const float *y, *H, *r, *nur, *adj;
  const float *W1w, *W1b, *b1, *Wm1w, *Wm1b, *Wm2w, *Wm2b;
  const float *gih, *ghh, *bih, *bhh, *W2w, *W2b, *b2;
  const float *Wr1w, *Wr1b, *Wr2w, *Wr2b;
  unsigned short* idxT;
  int* cnt;
  float *deg, *eg, *yhh, *u, *s, *out;
};

// ---------------------------------------------------------------------------
// shared math: msg-MLP + GRU step (weights pre-staged in sm)
// ---------------------------------------------------------------------------
template <bool FIRST>
__device__ __forceinline__ void mlp_gru(const float* __restrict__ sm,
                                        const float* uself, const float* msv,
                                        float d, float e, float xr9, float xn10,
                                        const float* sv, float* sn, float* un) {
  float agg[3 * NU];
#pragma unroll
  for (int o = 0; o < NU; ++o) {
    agg[o] = uself[o] * d;
    agg[NU + o] = msv[o];
    agg[2 * NU + o] = e;
  }
  float h1[NMLP];
#pragma unroll
  for (int h = 0; h < NMLP; ++h) {
    float t = sm[W_M1B + h];
#pragma unroll
    for (int i = 0; i < 3 * NU; ++i) t += sm[W_M1 + h * 3 * NU + i] * agg[i];
    h1[h] = fmaxf(t, 0.f);
  }
  float x[NU + 2];
#pragma unroll
  for (int o = 0; o < NU; ++o) {
    float t = sm[W_M2B + o];
#pragma unroll
    for (int h = 0; h < NMLP; ++h) t += sm[W_M2 + o * NMLP + h] * h1[h];
    x[o] = t;
  }
  x[NU] = xr9;
  x[NU + 1] = xn10;

#pragma unroll
  for (int g = 0; g < NH; ++g) {
    float xr = sm[W_BIH + g], xz = sm[W_BIH + NH + g], xn = sm[W_BIH + 2 * NH + g];
#pragma unroll
    for (int i = 0; i < NU + 2; ++i) {
      xr += sm[W_GIH + g * (NU + 2) + i] * x[i];
      xz += sm[W_GIH + (NH + g) * (NU + 2) + i] * x[i];
      xn += sm[W_GIH + (2 * NH + g) * (NU + 2) + i] * x[i];
    }
    float hr = sm[W_BHH + g], hz = sm[W_BHH + NH + g], hn = sm[W_BHH + 2 * NH + g];
    if (!FIRST) {
#pragma unroll
      for (int i = 0; i < NH; ++i) {
        hr += sm[W_GHH + g * NH + i] * sv[i];
        hz += sm[W_GHH + (NH + g) * NH + i] * sv[i];
        hn += sm[W_GHH + (2 * NH + g) * NH + i] * sv[i];
      }
    }
    float rg = 1.f / (1.f + expf(-(xr + hr)));
    float zg = 1.f / (1.f + expf(-(xz + hz)));
    float ng = tanhf(xn + rg * hn);
    sn[g] = FIRST ? (1.f - zg) * ng : ((1.f - zg) * ng + zg * sv[g]);
  }
#pragma unroll
  for (int o = 0; o < NU; ++o) {
    float t = sm[W_W2B + o];
#pragma unroll
    for (int h = 0; h < NH; ++h) t += sm[W_W2 + o * NH + h] * sn[h];
    un[o] = t;
  }
}

__device__ __forceinline__ void do_readout(const float* __restrict__ sm,
                                           const float* un,
                                           float* __restrict__ out, int node) {
  float h2[NMLP];
#pragma unroll
  for (int h = 0; h < NMLP; ++h) {
    float t = sm[W_R1B + h];
#pragma unroll
    for (int o = 0; o < NU; ++o) t += sm[W_R1 + h * NU + o] * un[o];
    h2[h] = fmaxf(t, 0.f);
  }
  float l0 = sm[W_R2B], l1 = sm[W_R2B + 1];
#pragma unroll
  for (int h = 0; h < NMLP; ++h) {
    l0 += sm[W_R2 + h] * h2[h];
    l1 += sm[W_R2 + NMLP + h] * h2[h];
  }
  float mx = fmaxf(l0, l1);
  float e0 = expf(l0 - mx), e1 = expf(l1 - mx);
  float inv = 1.f / (e0 + e1);
  float p0 = e0 * inv, p1 = e1 * inv;
  const float q0 = -0.70710678118654752f, q1 = 0.70710678118654752f;
  float xh = p0 * q0 + p1 * q1;
  float nu = p0 * (q0 - xh) * (q0 - xh) + p1 * (q1 - xh) * (q1 - xh);
  out[node] = xh;
  out[NBN + node] = fmaxf(nu, 1e-10f);
}

__device__ __forceinline__ void stage_weights(const KParams& P, float* sm,
                                              int tid, int nthr) {
  auto cp = [&](int dst, const float* so, int n) {
    for (int t = tid; t < n; t += nthr) sm[dst + t] = so[t];
  };
  cp(W_M1, P.Wm1w, NMLP * 3 * NU); cp(W_M1B, P.Wm1b, NMLP);
  cp(W_M2, P.Wm2w, NU * NMLP);     cp(W_M2B, P.Wm2b, NU);
  cp(W_GIH, P.gih, 36 * (NU + 2)); cp(W_GHH, P.ghh, 36 * NH);
  cp(W_BIH, P.bih, 36);            cp(W_BHH, P.bhh, 36);
  cp(W_W2, P.W2w, NU * NH);
  cp(W_R1, P.Wr1w, NMLP * NU);     cp(W_R1B, P.Wr1b, NMLP);
  cp(W_R2, P.Wr2w, 2 * NMLP);      cp(W_R2B, P.Wr2b, 2);
  cp(W_W1, P.W1w, 2 * NU);
  for (int t = tid; t < NU; t += nthr) {
    sm[W_W2B + t] = P.W2b[t] + P.b2[t];
    sm[W_W1B + t] = P.W1b[t] + P.b1[t];
  }
}

// ---------------------------------------------------------------------------
// adjacency-row scan body (one wave, one row)
// ---------------------------------------------------------------------------
__device__ __forceinline__ void build_row(const KParams& P, int row, int lane) {
  const float4* arow = (const float4*)(P.adj + (size_t)row * NN);
  float4 v[4];
#pragma unroll
  for (int rep = 0; rep < 4; ++rep) v[rep] = arow[rep * 64 + lane];
  const unsigned long long ltmask = (1ull << lane) - 1ull;
  int base = 0;
#pragma unroll
  for (int rep = 0; rep < 4; ++rep) {
    float c[4] = {v[rep].x, v[rep].y, v[rep].z, v[rep].w};
#pragma unroll
    for (int cc = 0; cc < 4; ++cc) {
      bool nz = (c[cc] != 0.0f);
      unsigned long long m = __ballot(nz);
      if (nz) {
        int p = base + __popcll(m & ltmask);
        if (p < MAXN)
          P.idxT[(size_t)p * NBN + row] =
              (unsigned short)(rep * 256 + lane * 4 + cc);
      }
      base += __popcll(m);
    }
  }
  if (lane == 0) {
    P.cnt[row] = base < MAXN ? base : MAXN;
    P.deg[row] = (float)base;
    P.eg[row] = 0.f;
    P.yhh[2 * row] = 0.f;
    P.yhh[2 * row + 1] = 0.f;
  }
}

// ---------------------------------------------------------------------------
// eg-tile body: stage 16 H-rows transposed+swizzled, yh/hh partials, eg gather
// ---------------------------------------------------------------------------
template <int NTHR>
__device__ __forceinline__ void eg_tile(const KParams& P, float* hsT, int bc,
                                        int tid) {
  const int b = bc >> 6;
  const int k0 = (bc & 63) * KC;
  const float* Hb = P.H + ((size_t)b * NN + k0) * NN;
  for (int j0 = tid; j0 < NN; j0 += NTHR) {
    float hv[KC];
#pragma unroll
    for (int k = 0; k < KC; ++k) hv[k] = Hb[(size_t)k * NN + j0];
#pragma unroll
    for (int c = 0; c < 4; ++c)
      *(float4*)&hsT[QSW(j0, c)] = ((const float4*)hv)[c];
  }
  __syncthreads();

  {
    float yv[KC];
#pragma unroll
    for (int k = 0; k < KC; ++k) yv[k] = P.y[b * NN + k0 + k];
    for (int j = tid; j < NN; j += NTHR) {
      float hv[KC];
#pragma unroll
      for (int c = 0; c < 4; ++c)
        ((float4*)hv)[c] = *(const float4*)&hsT[QSW(j, c)];
      float py = 0.f, ph = 0.f;
#pragma unroll
      for (int k = 0; k < KC; ++k) { py += yv[k] * hv[k]; ph += hv[k] * hv[k]; }
      atomicAdd(&P.yhh[(b * NN + j) * 2], py);
      atomicAdd(&P.yhh[(b * NN + j) * 2 + 1], ph);
    }
  }

  for (int rep = 0; rep < NN / NTHR; ++rep) {
    const int i = rep * NTHR + tid;
    const int node = b * NN + i;
    const int nnz = P.cnt[node];
    float hi[KC];
#pragma unroll
    for (int c = 0; c < 4; ++c)
      ((float4*)hi)[c] = *(const float4*)&hsT[QSW(i, c)];
    float a0 = 0.f, a1 = 0.f, a2 = 0.f, a3 = 0.f;
    int off = node;
#pragma unroll 2
    for (int t = 0; t < nnz; ++t) {
      const int j = (int)P.idxT[off]; off += NBN;
      float hj[KC];
#pragma unroll
      for (int c = 0; c < 4; ++c)
        ((float4*)hj)[c] = *(const float4*)&hsT[QSW(j, c)];
#pragma unroll
      for (int k = 0; k < 4; ++k) {
        a0 += hi[k] * hj[k];
        a1 += hi[4 + k] * hj[4 + k];
        a2 += hi[8 + k] * hj[8 + k];
        a3 += hi[12 + k] * hj[12 + k];
      }
    }
    atomicAdd(&P.eg[node], (a0 + a1) + (a2 + a3));
  }
}

// ===========================================================================
// FALLBACK PATH (3 kernels)
// ===========================================================================
__global__ __launch_bounds__(256) void k_build_idx(KParams P) {
  build_row(P, blockIdx.x * 4 + (threadIdx.x >> 6), threadIdx.x & 63);
}

__global__ __launch_bounds__(EGB) void k_eg(KParams P) {
  __shared__ float hsT[NN * KC];  // 64 KB
  eg_tile<EGB>(P, hsT, blockIdx.x, threadIdx.x);
}

// fused iter1 + iter2 + readout: one block per batch, u in LDS, s in regs
__global__ __launch_bounds__(NN, 4) void k_fin(KParams P) {
  __shared__ float su[NN * NU];  // 32 KB
  __shared__ float sm[W_SZ];
  const int tid = threadIdx.x, b = blockIdx.x;
  stage_weights(P, sm, tid, NN);
  __syncthreads();

  const int node = b * NN + tid;
  const int nnz = P.cnt[node];
  const float d = P.deg[node], e = P.eg[node];
  const float rr = P.r[node];
  const float nu = fmaxf(P.nur[node], 1e-10f);

  // ---- iter1: u0 linear in (yh,hh) -> gather collapses to sums
  float sy = 0.f, sh = 0.f;
  {
    int off = node;
#pragma unroll 4
    for (int t = 0; t < nnz; ++t) {
      const int j = (int)P.idxT[off]; off += NBN;
      float2 v = ((const float2*)P.yhh)[b * NN + j];
      sy += v.x; sh += v.y;
    }
  }
  const float2 w0 = ((const float2*)P.yhh)[node];
  float uself[NU], msv[NU];
  const float fn = (float)nnz;
#pragma unroll
  for (int o = 0; o < NU; ++o) {
    const float wa = sm[W_W1 + 2 * o], wb = sm[W_W1 + 2 * o + 1];
    const float bb = sm[W_W1B + o];
    uself[o] = w0.x * wa + w0.y * wb + bb;
    msv[o] = sy * wa + sh * wb + fn * bb;
  }
  float sv[NH], sn[NH], un[NU];
  mlp_gru<true>(sm, uself, msv, d, e, rr, nu, sv, sn, un);

  // publish u to LDS (swizzled granules; conflict-free staging writes)
#pragma unroll
  for (int c = 0; c < 2; ++c) *(float4*)&su[USW(tid, c)] = ((float4*)un)[c];
  __syncthreads();

  // ---- iter2: gather u from LDS; s carried in registers (sn)
  float4 acc0 = {0, 0, 0, 0}, acc1 = {0, 0, 0, 0};
  {
    int off = node;
#pragma unroll 4
    for (int t = 0; t < nnz; ++t) {
      const int j = (int)P.idxT[off]; off += NBN;
      float4 a = *(const float4*)&su[USW(j, 0)];
      float4 c4 = *(const float4*)&su[USW(j, 1)];
      acc0.x += a.x;  acc0.y += a.y;  acc0.z += a.z;  acc0.w += a.w;
      acc1.x += c4.x; acc1.y += c4.y; acc1.z += c4.z; acc1.w += c4.w;
    }
  }
  msv[0] = acc0.x; msv[1] = acc0.y; msv[2] = acc0.z; msv[3] = acc0.w;
  msv[4] = acc1.x; msv[5] = acc1.y; msv[6] = acc1.z; msv[7] = acc1.w;
  float sn2[NH], un2[NU];
  mlp_gru<false>(sm, un, msv, d, e, rr, nu, sn, sn2, un2);
  do_readout(sm, un2, P.out, node);
}

// ===========================================================================
// COOPERATIVE PATH (single kernel, 256 blocks x 512 thr, 1 block/CU margin)
// ===========================================================================
__global__ __launch_bounds__(BLK, 2) void k_all(KParams P) {
  __shared__ float smem[NN * KC];  // 64 KB: hsT during eg, weights after
  cg::grid_group gg = cg::this_grid();
  const int tid = threadIdx.x, bid = blockIdx.x;
  const int wave = tid >> 6, lane = tid & 63;

  // phase 0: adjacency scan (64 rows/block)
#pragma unroll
  for (int rr = 0; rr < 8; ++rr)
    build_row(P, bid * 64 + wave * 8 + rr, lane);
  gg.sync();

  // phase 1: eg/yh/hh over 1024 tiles, 4 per block
  for (int bc = bid; bc < NB * (NN / KC); bc += GRID2) {
    __syncthreads();
    eg_tile<BLK>(P, smem, bc, tid);
  }
  gg.sync();

  // weights into smem (safe: all blocks past phase 1)
  stage_weights(P, smem, tid, BLK);
  __syncthreads();

  // phase 2: iter1 (writes u, s)
  for (int node = bid * BLK + tid; node < NBN; node += GRID2 * BLK) {
    const int nnz = P.cnt[node];
    const int bb = node & ~(NN - 1);
    float sy = 0.f, sh = 0.f;
    int off = node;
#pragma unroll 4
    for (int t = 0; t < nnz; ++t) {
      const int j = (int)P.idxT[off]; off += NBN;
      float2 v = ((const float2*)P.yhh)[bb + j];
      sy += v.x; sh += v.y;
    }
    const float2 w0 = ((const float2*)P.yhh)[node];
    float uself[NU], msv[NU];
    const float fn = (float)nnz;
#pragma unroll
    for (int o = 0; o < NU; ++o) {
      const float wa = smem[W_W1 + 2 * o], wb = smem[W_W1 + 2 * o + 1];
      const float bbv = smem[W_W1B + o];
      uself[o] = w0.x * wa + w0.y * wb + bbv;
      msv[o] = sy * wa + sh * wb + fn * bbv;
    }
    float sv[NH], sn[NH], un[NU];
    mlp_gru<true>(smem, uself, msv, P.deg[node], P.eg[node], P.r[node],
                  fmaxf(P.nur[node], 1e-10f), sv, sn, un);
#pragma unroll
    for (int g = 0; g < NH; ++g) P.s[(size_t)node * NH + g] = sn[g];
#pragma unroll
    for (int o = 0; o < NU; ++o) P.u[(size_t)node * NU + o] = un[o];
  }
  gg.sync();

  // phase 3: iter2 + readout
  for (int node = bid * BLK + tid; node < NBN; node += GRID2 * BLK) {
    const int nnz = P.cnt[node];
    const int bb = node & ~(NN - 1);
    float4 acc0 = {0, 0, 0, 0}, acc1 = {0, 0, 0, 0};
    int off = node;
#pragma unroll 4
    for (int t = 0; t < nnz; ++t) {
      const int j = (int)P.idxT[off]; off += NBN;
      const float4* up = (const float4*)(P.u + ((size_t)bb + j) * NU);
      float4 a = up[0], c4 = up[1];
      acc0.x += a.x;  acc0.y += a.y;  acc0.z += a.z;  acc0.w += a.w;
      acc1.x += c4.x; acc1.y += c4.y; acc1.z += c4.z; acc1.w += c4.w;
    }
    float uself[NU], msv[NU];
    msv[0] = acc0.x; msv[1] = acc0.y; msv[2] = acc0.z; msv[3] = acc0.w;
    msv[4] = acc1.x; msv[5] = acc1.y; msv[6] = acc1.z; msv[7] = acc1.w;
    const float4* up = (const float4*)(P.u + (size_t)node * NU);
    float4 a = up[0], c4 = up[1];
    uself[0] = a.x;  uself[1] = a.y;  uself[2] = a.z;  uself[3] = a.w;
    uself[4] = c4.x; uself[5] = c4.y; uself[6] = c4.z; uself[7] = c4.w;
    float sv[NH], sn[NH], un[NU];
#pragma unroll
    for (int g = 0; g < NH; ++g) sv[g] = P.s[(size_t)node * NH + g];
    mlp_gru<false>(smem, uself, msv, P.deg[node], P.eg[node], P.r[node],
                   fmaxf(P.nur[node], 1e-10f), sv, sn, un);
    do_readout(smem, un, P.out, node);
  }
}

// ---------------------------------------------------------------------------
extern "C" void kernel_launch(void* const* d_in, const int* in_sizes, int n_in,
                              void* d_out, int out_size, void* d_ws,
                              size_t ws_size, hipStream_t stream) {
  char* p = (char*)d_ws;
  auto carve = [&](size_t bytes) {
    void* q = (void*)p;
    p += (bytes + 255) & ~(size_t)255;
    return q;
  };
  unsigned short* idxT = (unsigned short*)carve((size_t)MAXN * NBN * 2);
  int*   cnt = (int*)  carve((size_t)NBN * 4);
  float* deg = (float*)carve((size_t)NBN * 4);
  float* eg  = (float*)carve((size_t)NBN * 4);
  float* yhh = (float*)carve((size_t)NBN * 8);
  float* u   = (float*)carve((size_t)NBN * NU * 4);
  float* s   = (float*)carve((size_t)NBN * NH * 4);

  KParams prm;
  prm.y    = (const float*)d_in[0];
  prm.H    = (const float*)d_in[1];
  prm.r    = (const float*)d_in[2];
  prm.nur  = (const float*)d_in[3];
  prm.adj  = (const float*)d_in[4];
  prm.W1w  = (const float*)d_in[5];
  prm.W1b  = (const float*)d_in[6];
  prm.b1   = (const float*)d_in[7];
  prm.Wm1w = (const float*)d_in[8];
  prm.Wm1b = (const float*)d_in[9];
  prm.Wm2w = (const float*)d_in[10];
  prm.Wm2b = (const float*)d_in[11];
  prm.gih  = (const float*)d_in[12];
  prm.ghh  = (const float*)d_in[13];
  prm.bih  = (const float*)d_in[14];
  prm.bhh  = (const float*)d_in[15];
  prm.W2w  = (const float*)d_in[16];
  prm.W2b  = (const float*)d_in[17];
  prm.b2   = (const float*)d_in[18];
  prm.Wr1w = (const float*)d_in[19];
  prm.Wr1b = (const float*)d_in[20];
  prm.Wr2w = (const float*)d_in[21];
  prm.Wr2b = (const float*)d_in[22];
  prm.idxT = idxT; prm.cnt = cnt; prm.deg = deg; prm.eg = eg;
  prm.yhh = yhh; prm.u = u; prm.s = s;
  prm.out = (float*)d_out;

  // capture-safe host queries: only attempt coop if it will actually fit
  int dev = 0;
  (void)hipGetDevice(&dev);
  int coop = 0, ncu = 0, maxb = 0;
  (void)hipDeviceGetAttribute(&coop, hipDeviceAttributeCooperativeLaunch, dev);
  (void)hipDeviceGetAttribute(&ncu, hipDeviceAttributeMultiprocessorCount, dev);
  (void)hipOccupancyMaxActiveBlocksPerMultiprocessor(&maxb, k_all, BLK, 0);

  hipError_t e = hipErrorUnknown;
  if (coop && (size_t)maxb * (size_t)ncu >= GRID2) {
    void* args[] = {(void*)&prm};
    e = hipLaunchCooperativeKernel((void*)k_all, dim3(GRID2), dim3(BLK), args,
                                   0, stream);
  }
  if (e != hipSuccess) {
    (void)hipGetLastError();  // clear
    k_build_idx<<<NBN / 4, 256, 0, stream>>>(prm);
    k_eg<<<NB * (NN / KC), EGB, 0, stream>>>(prm);
    k_fin<<<NB, NN, 0, stream>>>(prm);
  }
}